// Round 1
// baseline (438.244 us; speedup 1.0000x reference)
//
#include <hip/hip_runtime.h>
#include <math.h>

// Problem constants
#define BATCH 32
#define CIn   32
#define COut  64
#define NXS   256
#define NYS   256
#define KX2   64            // 2*modes1
#define KYN   33            // modes2+1
#define MODES (KX2*KYN)     // 2112

// ws float offsets
#define OFF_T1   0          // 16896 floats: interleaved (c,s) per (y,ky), scaled by 1/65536
#define OFF_T2C  16896      // 16384 floats: [x][kx] cos
#define OFF_T2S  33280      // 16384 floats: [x][kx] -sin
#define OFF_XTR  49664      // 1024*2112
#define OFF_XTI  2212352    // 1024*2112
#define OFF_PART 4375040    // 64*2048
// total: 4506112 floats = ~18 MB of ws

// ---------------------------------------------------------------------------
// Twiddle tables (computed on device each call; tiny)
// ---------------------------------------------------------------------------
__global__ void fno_twiddle(float* __restrict__ t1,
                            float* __restrict__ t2c,
                            float* __restrict__ t2s) {
    int idx = blockIdx.x * 256 + threadIdx.x;
    const float w0 = 6.28318530717958647692f / 256.0f;
    if (idx < 256 * 33) {
        int y  = idx / 33;
        int ky = idx - y * 33;
        int m  = (y * ky) & 255;
        float sg, cg;
        sincosf(w0 * (float)m, &sg, &cg);
        t1[2 * idx]     =  cg * (1.0f / 65536.0f);
        t1[2 * idx + 1] = -sg * (1.0f / 65536.0f);
    }
    if (idx < 256 * 64) {
        int xx = idx >> 6;
        int kx = idx & 63;
        int kxa = (kx < 32) ? kx : (kx + 192);   // rows 32..63 are kx 224..255
        int m = (xx * kxa) & 255;
        float sg, cg;
        sincosf(w0 * (float)m, &sg, &cg);
        t2c[idx] =  cg;
        t2s[idx] = -sg;
    }
}

// ---------------------------------------------------------------------------
// Fused stage 1 (y-DFT, 33 modes) + stage 2 (x-DFT, 64 modes) per plane
// One block per (b,i) plane. 256 threads.
// ---------------------------------------------------------------------------
struct SmA { float xl[256][33]; float2 t1[32][36]; };  // 33792 + 9216 B
struct SmB { float y[256][66]; };                       // 67584 B

__global__ __launch_bounds__(256, 2)
void fno_stage12(const float* __restrict__ x,
                 const float* __restrict__ t1g,
                 const float* __restrict__ t2c,
                 const float* __restrict__ t2s,
                 float* __restrict__ XTr,
                 float* __restrict__ XTi) {
    __shared__ union { SmA a; SmB b; } sm;

    const int tid = threadIdx.x;
    const int p   = blockIdx.x;                // plane = b*CIn + i
    const float* xp = x + (size_t)p * (NXS * NYS);

    // Phase A thread mapping: 64 row-groups x 4 ky-groups
    const int mt  = tid & 63;                  // owns rows mt, mt+64, mt+128, mt+192
    const int w   = tid >> 6;                  // wave id -> ky group
    const int kst = w * 9;                     // ky chunk start (9,9,9,6 real)

    float accr[4][9], acci[4][9];
#pragma unroll
    for (int j = 0; j < 4; ++j)
#pragma unroll
        for (int k = 0; k < 9; ++k) { accr[j][k] = 0.f; acci[j][k] = 0.f; }

    const float2* t1f2 = (const float2*)t1g;

    for (int cc = 0; cc < 256; cc += 32) {
        // stage x chunk: all 256 rows, cols cc..cc+31 (coalesced float4)
        for (int e = tid; e < 2048; e += 256) {
            int r  = e >> 3;
            int c4 = e & 7;
            float4 v = *(const float4*)(xp + r * 256 + cc + c4 * 4);
            float* d = &sm.a.xl[r][c4 * 4];
            d[0] = v.x; d[1] = v.y; d[2] = v.z; d[3] = v.w;
        }
        // stage t1 chunk [32][36] (cols >= 33 zero-padded)
        for (int e = tid; e < 32 * 36; e += 256) {
            int yy = e / 36;
            int k  = e - yy * 36;
            float2 v = (k < 33) ? t1f2[(cc + yy) * 33 + k] : make_float2(0.f, 0.f);
            sm.a.t1[yy][k] = v;
        }
        __syncthreads();

#pragma unroll 2
        for (int yy = 0; yy < 32; ++yy) {
            float a0 = sm.a.xl[mt      ][yy];
            float a1 = sm.a.xl[mt +  64][yy];
            float a2 = sm.a.xl[mt + 128][yy];
            float a3 = sm.a.xl[mt + 192][yy];
#pragma unroll
            for (int k = 0; k < 9; ++k) {
                float2 cs = sm.a.t1[yy][kst + k];   // broadcast within wave
                accr[0][k] += a0 * cs.x; acci[0][k] += a0 * cs.y;
                accr[1][k] += a1 * cs.x; acci[1][k] += a1 * cs.y;
                accr[2][k] += a2 * cs.x; acci[2][k] += a2 * cs.y;
                accr[3][k] += a3 * cs.x; acci[3][k] += a3 * cs.y;
            }
        }
        __syncthreads();
    }

    // Write row-spectrum Y into LDS: y[x][2*ky + (0=re,1=im)]
#pragma unroll
    for (int j = 0; j < 4; ++j) {
#pragma unroll
        for (int k = 0; k < 9; ++k) {
            int ky = kst + k;
            if (ky < 33) {
                sm.b.y[mt + 64 * j][2 * ky    ] = accr[j][k];
                sm.b.y[mt + 64 * j][2 * ky + 1] = acci[j][k];
            }
        }
    }
    __syncthreads();

    // Phase B: xt[kx][ky] = sum_x Y[x][ky] * E[x][kx]
    const int kx = tid & 63;       // fixed kx per thread
    const int wb = tid >> 6;
    int c0[9];
#pragma unroll
    for (int q = 0; q < 9; ++q) {
        int ky = 4 * q + wb;
        c0[q] = 2 * (ky < 33 ? ky : 32);   // clamp (discarded on write)
    }
    float pr[9], pi[9];
#pragma unroll
    for (int q = 0; q < 9; ++q) { pr[q] = 0.f; pi[q] = 0.f; }

    const float* t2cp = t2c + kx;
    const float* t2sp = t2s + kx;
#pragma unroll 2
    for (int xx = 0; xx < 256; ++xx) {
        float c = t2cp[(size_t)xx * 64];   // coalesced across lanes, L2-hot
        float s = t2sp[(size_t)xx * 64];
#pragma unroll
        for (int q = 0; q < 9; ++q) {
            float yr = sm.b.y[xx][c0[q]];      // broadcast within wave
            float yi = sm.b.y[xx][c0[q] + 1];
            pr[q] += yr * c - yi * s;
            pi[q] += yr * s + yi * c;
        }
    }

    // Write truncated spectrum with signed mode-sum weights folded in
    float* xtr = XTr + (size_t)p * MODES;
    float* xti = XTi + (size_t)p * MODES;
#pragma unroll
    for (int q = 0; q < 9; ++q) {
        int ky = 4 * q + wb;
        if (ky < 33) {
            float sc = (kx < 32) ? ((kx == 0 && ky == 0) ? 1.f : 2.f)
                                 : ((ky == 0) ? 0.f : 2.f);
            xtr[kx * 33 + ky] = sc * pr[q];
            xti[kx * 33 + ky] = sc * pi[q];
        }
    }
}

// ---------------------------------------------------------------------------
// Stage 3: out[b,o] = sum_{i,m} XTr*Wr - XTi*Wi  (split-K partials, no atomics)
// grid: 32 i * 8 o-groups * 2 m-halves = 512 blocks; thread = (b, o within group)
// ---------------------------------------------------------------------------
__global__ __launch_bounds__(256)
void fno_stage3(const float* __restrict__ XTr, const float* __restrict__ XTi,
                const float* __restrict__ Wr,  const float* __restrict__ Wi,
                float* __restrict__ part) {
    const int bid = blockIdx.x;
    const int i   = bid >> 4;
    const int og  = (bid >> 1) & 7;
    const int h   = bid & 1;
    const int tid = threadIdx.x;
    const int bb  = tid & 31;
    const int oo  = og * 8 + (tid >> 5);

    const float4* xr = (const float4*)(XTr + (size_t)(bb * CIn + i) * MODES + h * 1056);
    const float4* xi = (const float4*)(XTi + (size_t)(bb * CIn + i) * MODES + h * 1056);
    const float4* wr = (const float4*)(Wr  + (size_t)(i * COut + oo) * MODES + h * 1056);
    const float4* wi = (const float4*)(Wi  + (size_t)(i * COut + oo) * MODES + h * 1056);

    float acc = 0.f;
#pragma unroll 4
    for (int m = 0; m < 264; ++m) {          // 264 float4 = 1056 modes per half
        float4 a = xr[m], br = wr[m];
        float4 c = xi[m], bi = wi[m];
        acc += a.x * br.x + a.y * br.y + a.z * br.z + a.w * br.w;
        acc -= c.x * bi.x + c.y * bi.y + c.z * bi.z + c.w * bi.w;
    }
    part[(size_t)(((i << 1) | h) * BATCH + bb) * COut + oo] = acc;
}

__global__ void fno_reduce(const float* __restrict__ part, float* __restrict__ out) {
    int idx = blockIdx.x * 256 + threadIdx.x;   // b*64 + o
    float s = 0.f;
#pragma unroll 8
    for (int j = 0; j < 64; ++j) s += part[(size_t)j * 2048 + idx];
    out[idx] = s;
}

// ---------------------------------------------------------------------------
extern "C" void kernel_launch(void* const* d_in, const int* in_sizes, int n_in,
                              void* d_out, int out_size, void* d_ws, size_t ws_size,
                              hipStream_t stream) {
    const float* x  = (const float*)d_in[0];
    const float* wr = (const float*)d_in[1];
    const float* wi = (const float*)d_in[2];
    float* out = (float*)d_out;
    float* ws  = (float*)d_ws;

    float* t1   = ws + OFF_T1;
    float* t2c  = ws + OFF_T2C;
    float* t2s  = ws + OFF_T2S;
    float* XTr  = ws + OFF_XTR;
    float* XTi  = ws + OFF_XTI;
    float* part = ws + OFF_PART;

    fno_twiddle<<<64, 256, 0, stream>>>(t1, t2c, t2s);
    fno_stage12<<<BATCH * CIn, 256, 0, stream>>>(x, t1, t2c, t2s, XTr, XTi);
    fno_stage3<<<512, 256, 0, stream>>>(XTr, XTi, wr, wi, part);
    fno_reduce<<<8, 256, 0, stream>>>(part, out);
}

// Round 2
// 309.802 us; speedup vs baseline: 1.4146x; 1.4146x over previous
//
#include <hip/hip_runtime.h>
#include <math.h>

#define BATCH 32
#define CIn   32
#define COut  64
#define NXS   256
#define NYS   256
#define MODES 2112

// ws float offsets
#define OFF_T1   0          // 129*33 float2 = 8514 floats (reserve 8704)
#define OFF_T2C  8704       // 16384
#define OFF_T2S  25088      // 16384
#define OFF_XTR  41472      // 1024*2112
#define OFF_XTI  2204160    // 1024*2112
#define OFF_PART 4366848    // 256*2048
// total 4891136 floats = 19.6 MB

// ---------------------------------------------------------------------------
// Twiddles. t1: rows y=0..128, (cos, -sin)*scale, row 128 half-weight (self-pair).
// t2: [x][kx] for kx mapping 0..31 -> kx, 32..63 -> kx+192.
// ---------------------------------------------------------------------------
__global__ void fno_twiddle(float* __restrict__ t1,
                            float* __restrict__ t2c,
                            float* __restrict__ t2s) {
    int idx = blockIdx.x * 256 + threadIdx.x;
    const float w0 = 6.28318530717958647692f / 256.0f;
    const float sc = 1.0f / 65536.0f;
    if (idx < 129 * 33) {
        int y = idx / 33, ky = idx - y * 33;
        int m = (y * ky) & 255;
        float sg, cg; sincosf(w0 * (float)m, &sg, &cg);
        float w = (y == 128) ? 0.5f : 1.0f;
        t1[2 * idx]     =  cg * sc * w;
        t1[2 * idx + 1] = -sg * sc * w;
    }
    if (idx < 256 * 64) {
        int xx = idx >> 6, kx = idx & 63;
        int kxa = (kx < 32) ? kx : kx + 192;
        int m = (xx * kxa) & 255;
        float sg, cg; sincosf(w0 * (float)m, &sg, &cg);
        t2c[idx] =  cg;
        t2s[idx] = -sg;
    }
}

// ---------------------------------------------------------------------------
// Fused y-DFT (folded pairs) + x-DFT (folded pairs). 1 block per plane, 1024 thr.
// ---------------------------------------------------------------------------
struct PA { float xf[256][17]; float xb[256][17]; float2 t1[16][40]; }; // 39936 B
struct PB { float y[256][66]; };                                        // 67584 B

__global__ __launch_bounds__(1024, 8)
void fno_stage12(const float* __restrict__ x, const float* __restrict__ t1g,
                 const float* __restrict__ t2c, const float* __restrict__ t2s,
                 float* __restrict__ XTr, float* __restrict__ XTi) {
    __shared__ union { PA a; PB b; } sm;
    const int tid = threadIdx.x;
    const int p   = blockIdx.x;
    const float* xp = x + (size_t)p * (NXS * NYS);

    // ---- Phase A: thread owns row r, ky group g (ky = 9g..9g+8) ----
    const int r = tid & 255;
    const int g = tid >> 8;

    float accr[9], acci[9];
    {
        float x0 = xp[r * 256] * (1.0f / 65536.0f);   // y=0 column: cos=1 all ky
#pragma unroll
        for (int k = 0; k < 9; ++k) { accr[k] = x0; acci[k] = 0.f; }
    }

    const float2* t1f2 = (const float2*)t1g;

    for (int j = 0; j < 8; ++j) {
        const int c0 = 16 * j + 1;     // front cols [c0, c0+16)  -> y = 1..128
        const int cb = 240 - 16 * j;   // back  cols [cb, cb+16)  -> mirrors
        // stage front (scalar, coalesced 64B runs)
        for (int f = tid; f < 4096; f += 1024) {
            int rr = f >> 4, cc = f & 15;
            sm.a.xf[rr][cc] = xp[rr * 256 + c0 + cc];
        }
        // stage back (float4, aligned)
        {
            int rr = tid >> 2, c4 = tid & 3;
            float4 v = *(const float4*)(xp + rr * 256 + cb + 4 * c4);
            sm.a.xb[rr][4 * c4 + 0] = v.x; sm.a.xb[rr][4 * c4 + 1] = v.y;
            sm.a.xb[rr][4 * c4 + 2] = v.z; sm.a.xb[rr][4 * c4 + 3] = v.w;
        }
        // stage t1 rows y=c0..c0+15, group-padded: group g2 at cols [10*g2, 10*g2+10)
        if (tid < 640) {
            int rr = tid / 40, c = tid - rr * 40;
            int g2 = c / 10, kk = c - g2 * 10;
            int ky = 9 * g2 + kk;
            sm.a.t1[rr][c] = (kk < 9 && ky < 33) ? t1f2[(c0 + rr) * 33 + ky]
                                                 : make_float2(0.f, 0.f);
        }
        __syncthreads();

        const float* xfr = sm.a.xf[r];
        const float* xbr = sm.a.xb[r];
#pragma unroll 2
        for (int t = 0; t < 16; ++t) {
            float fv = xfr[t], bv = xbr[15 - t];
            float u = fv + bv, v = fv - bv;
            const float2* t1r = &sm.a.t1[t][10 * g];
            float4 A = *(const float4*)&t1r[0];
            float4 Bq = *(const float4*)&t1r[2];
            float4 C = *(const float4*)&t1r[4];
            float4 D = *(const float4*)&t1r[6];
            float2 E = t1r[8];
            accr[0] += u * A.x;  acci[0] += v * A.y;
            accr[1] += u * A.z;  acci[1] += v * A.w;
            accr[2] += u * Bq.x; acci[2] += v * Bq.y;
            accr[3] += u * Bq.z; acci[3] += v * Bq.w;
            accr[4] += u * C.x;  acci[4] += v * C.y;
            accr[5] += u * C.z;  acci[5] += v * C.w;
            accr[6] += u * D.x;  acci[6] += v * D.y;
            accr[7] += u * D.z;  acci[7] += v * D.w;
            accr[8] += u * E.x;  acci[8] += v * E.y;
        }
        __syncthreads();
    }

    // write row spectrum Y to LDS
#pragma unroll
    for (int k = 0; k < 9; ++k) {
        int ky = 9 * g + k;
        if (ky < 33) {
            float2 v2; v2.x = accr[k]; v2.y = acci[k];
            *(float2*)&sm.b.y[r][2 * ky] = v2;
        }
    }
    __syncthreads();

    // ---- Phase B: thread = (kx, ky pair); fold x-pairs ----
    const int kx  = tid & 63;
    const int kyg = tid >> 6;              // wave id, uniform
    const float sgn = (kx & 1) ? -1.f : 1.f;
    const int ky0 = 2 * kyg, ky1 = 2 * kyg + 1;

    float2 e0 = *(const float2*)&sm.b.y[0][2 * ky0];
    float2 h0 = *(const float2*)&sm.b.y[128][2 * ky0];
    float2 e1 = *(const float2*)&sm.b.y[0][2 * ky1];
    float2 h1 = *(const float2*)&sm.b.y[128][2 * ky1];
    float pr0 = e0.x + sgn * h0.x, pi0 = e0.y + sgn * h0.y;
    float pr1 = e1.x + sgn * h1.x, pi1 = e1.y + sgn * h1.y;

    const float* t2cp = t2c + kx;
    const float* t2sp = t2s + kx;
    for (int xx = 1; xx < 128; ++xx) {
        float c  = t2cp[xx * 64];
        float sp = t2sp[xx * 64];          // = -sin
        float2 a0 = *(const float2*)&sm.b.y[xx][2 * ky0];
        float2 b0 = *(const float2*)&sm.b.y[256 - xx][2 * ky0];
        float ur = a0.x + b0.x, vr = a0.x - b0.x;
        float ui = a0.y + b0.y, vi = a0.y - b0.y;
        pr0 += ur * c - vi * sp;
        pi0 += ui * c + vr * sp;
        float2 a1 = *(const float2*)&sm.b.y[xx][2 * ky1];
        float2 b1 = *(const float2*)&sm.b.y[256 - xx][2 * ky1];
        ur = a1.x + b1.x; vr = a1.x - b1.x;
        ui = a1.y + b1.y; vi = a1.y - b1.y;
        pr1 += ur * c - vi * sp;
        pi1 += ui * c + vr * sp;
    }

    float* xtr = XTr + (size_t)p * MODES;
    float* xti = XTi + (size_t)p * MODES;
    {
        float w0s = (kx < 32) ? ((kx == 0 && ky0 == 0) ? 1.f : 2.f)
                              : ((ky0 == 0) ? 0.f : 2.f);
        xtr[kx * 33 + ky0] = w0s * pr0;
        xti[kx * 33 + ky0] = w0s * pi0;
        xtr[kx * 33 + ky1] = 2.f * pr1;    // ky1 >= 1 always
        xti[kx * 33 + ky1] = 2.f * pi1;
    }

    if (kyg == 15) {   // ky = 32 tail (wave-uniform branch)
        const int ky2 = 32;
        float2 e2 = *(const float2*)&sm.b.y[0][2 * ky2];
        float2 h2 = *(const float2*)&sm.b.y[128][2 * ky2];
        float pr2 = e2.x + sgn * h2.x, pi2 = e2.y + sgn * h2.y;
        for (int xx = 1; xx < 128; ++xx) {
            float c  = t2cp[xx * 64];
            float sp = t2sp[xx * 64];
            float2 a2 = *(const float2*)&sm.b.y[xx][2 * ky2];
            float2 b2 = *(const float2*)&sm.b.y[256 - xx][2 * ky2];
            float ur = a2.x + b2.x, vr = a2.x - b2.x;
            float ui = a2.y + b2.y, vi = a2.y - b2.y;
            pr2 += ur * c - vi * sp;
            pi2 += ui * c + vr * sp;
        }
        xtr[kx * 33 + ky2] = 2.f * pr2;
        xti[kx * 33 + ky2] = 2.f * pi2;
    }
}

// ---------------------------------------------------------------------------
// Stage 3: out[b,o] partials. Block = (i, m-chunk of 264). XT staged in LDS
// (coalesced float4); lanes = (o, m&3) so W loads hit 16B runs with L1 reuse.
// ---------------------------------------------------------------------------
__global__ __launch_bounds__(256)
void fno_stage3(const float* __restrict__ XTr, const float* __restrict__ XTi,
                const float* __restrict__ Wr,  const float* __restrict__ Wi,
                float* __restrict__ part) {
    __shared__ float sm3[2][32][268];
    const int i  = blockIdx.x >> 3;
    const int mc = blockIdx.x & 7;
    const int tid = threadIdx.x;
    const size_t mbase = (size_t)mc * 264;

    for (int f = tid; f < 4224; f += 256) {        // 2 arr * 32 b * 66 float4
        int arr = (f >= 2112);
        int gidx = f - arr * 2112;
        int b = gidx / 66, q = gidx - b * 66;
        const float* src = (arr ? XTi : XTr) + (size_t)(b * CIn + i) * MODES + mbase + 4 * q;
        float4 v = *(const float4*)src;
        *(float4*)&sm3[arr][b][4 * q] = v;
    }
    __syncthreads();

    const int o  = tid >> 2;
    const int ms = tid & 3;
    const float* wrp = Wr + (size_t)(i * COut + o) * MODES + mbase + ms;
    const float* wip = Wi + (size_t)(i * COut + o) * MODES + mbase + ms;

    float acc[32];
#pragma unroll
    for (int b = 0; b < 32; ++b) acc[b] = 0.f;

#pragma unroll 2
    for (int t = 0; t < 66; ++t) {
        float wr = wrp[4 * t], wi = wip[4 * t];
        int m = 4 * t + ms;
#pragma unroll
        for (int b = 0; b < 32; ++b)
            acc[b] += sm3[0][b][m] * wr - sm3[1][b][m] * wi;
    }

    __syncthreads();
    float* red = &sm3[0][0][0];                    // 32*256 floats reuse
#pragma unroll
    for (int b = 0; b < 32; ++b)
        red[b * 256 + o * 4 + ms] = acc[b];
    __syncthreads();

    for (int s = tid; s < 2048; s += 256) {
        int o2 = s >> 5, b2 = s & 31;
        float v = red[b2 * 256 + o2 * 4 + 0] + red[b2 * 256 + o2 * 4 + 1]
                + red[b2 * 256 + o2 * 4 + 2] + red[b2 * 256 + o2 * 4 + 3];
        part[(size_t)blockIdx.x * 2048 + s] = v;   // s = o2*32 + b2
    }
}

__global__ void fno_reduce(const float* __restrict__ part, float* __restrict__ out) {
    int idx = blockIdx.x * 256 + threadIdx.x;      // idx = b*64 + o
    int b = idx >> 6, o = idx & 63;
    float s = 0.f;
#pragma unroll 8
    for (int j = 0; j < 256; ++j) s += part[(size_t)j * 2048 + o * 32 + b];
    out[idx] = s;
}

// ---------------------------------------------------------------------------
extern "C" void kernel_launch(void* const* d_in, const int* in_sizes, int n_in,
                              void* d_out, int out_size, void* d_ws, size_t ws_size,
                              hipStream_t stream) {
    const float* x  = (const float*)d_in[0];
    const float* wr = (const float*)d_in[1];
    const float* wi = (const float*)d_in[2];
    float* out = (float*)d_out;
    float* ws  = (float*)d_ws;

    float* t1   = ws + OFF_T1;
    float* t2c  = ws + OFF_T2C;
    float* t2s  = ws + OFF_T2S;
    float* XTr  = ws + OFF_XTR;
    float* XTi  = ws + OFF_XTI;
    float* part = ws + OFF_PART;

    fno_twiddle<<<64, 256, 0, stream>>>(t1, t2c, t2s);
    fno_stage12<<<BATCH * CIn, 1024, 0, stream>>>(x, t1, t2c, t2s, XTr, XTi);
    fno_stage3<<<256, 256, 0, stream>>>(XTr, XTi, wr, wi, part);
    fno_reduce<<<8, 256, 0, stream>>>(part, out);
}

// Round 3
// 188.500 us; speedup vs baseline: 2.3249x; 1.6435x over previous
//
#include <hip/hip_runtime.h>
#include <math.h>

#define BATCH 32
#define CIn   32
#define COut  64
#define MODES 2112

typedef __attribute__((ext_vector_type(8))) short bf16x8;
typedef __attribute__((ext_vector_type(4))) float f32x4;

// ws byte offsets
#define OB_T1F  0u           // 20480 ushort = 40960 B
#define OB_A2F  40960u       // 32768 ushort = 65536 B
#define OB_Y    106496u      // 262144*66*2 = 34603008 B
#define OB_XTR  34709504u    // 1024*2112*4
#define OB_XTI  43360256u
#define OB_PART 52011008u    // 256*2048*4

__device__ __forceinline__ ushort f2bf(float f) {
    union { float f; uint u; } v; v.f = f;
    uint r = (v.u + 0x7FFFu + ((v.u >> 16) & 1u)) >> 16;
    return (ushort)r;
}

// n-tile base columns: tile 4 covers cols 50..65 (only 64,65 newly stored)
#define NB0 0
#define NB1 16
#define NB2 32
#define NB3 48
#define NB4 50

// ---------------------------------------------------------------------------
// Twiddle tables in MFMA-fragment-linear layout.
// T1f[((c*5+t)*64+l)*8+i] = B1[k=32c+8(l>>4)+i][n=nb(t)+(l&15)]
//   B1[k][2ky+s] = (s ? -sin : cos)(2*pi*k*ky/256) / 65536
// A2f[((c*4+mt)*64+l)*8+i] = A2[kx=mt*16+(l&15)][kk=32c+8(l>>4)+i]
//   A2[kx][2x+s] = (s ? -sin : cos)(2*pi*kxa*x/256), kxa = kx<32?kx:kx+192
// ---------------------------------------------------------------------------
__global__ void fno_tw(ushort* __restrict__ T1f, ushort* __restrict__ A2f) {
    const int nb[5] = {NB0, NB1, NB2, NB3, NB4};
    int idx = blockIdx.x * 256 + threadIdx.x;
    const float w0 = 6.28318530717958647692f / 256.0f;
    if (idx < 20480) {
        int i = idx & 7, l = (idx >> 3) & 63, ct = idx >> 9;
        int c = ct / 5, t = ct - 5 * c;
        int k = 32 * c + 8 * (l >> 4) + i;
        int n = nb[t] + (l & 15);
        int ky = n >> 1, s = n & 1;
        int m = (k * ky) & 255;
        float v = s ? -sinf(w0 * (float)m) : cosf(w0 * (float)m);
        T1f[idx] = f2bf(v * (1.0f / 65536.0f));
    }
    if (idx < 32768) {
        int i = idx & 7, l = (idx >> 3) & 63, cm = idx >> 9;
        int c = cm >> 2, mt = cm & 3;
        int kk = 32 * c + 8 * (l >> 4) + i;
        int kx = mt * 16 + (l & 15);
        int x = kk >> 1, s = kk & 1;
        int kxa = (kx < 32) ? kx : kx + 192;
        int m = (x * kxa) & 255;
        float v = s ? -sinf(w0 * (float)m) : cosf(w0 * (float)m);
        A2f[idx] = f2bf(v);
    }
}

// ---------------------------------------------------------------------------
// K1: Y = X @ T1  (M=262144, K=256, N=66). B-frags in registers, A direct
// from global in fragment order, no LDS, no barriers. Y stored bf16.
// ---------------------------------------------------------------------------
__global__ __launch_bounds__(256, 2)
void fno_gemm1(const float* __restrict__ x, const ushort* __restrict__ T1f,
               ushort* __restrict__ Y) {
    const int lane = threadIdx.x & 63;
    const int wg   = (blockIdx.x << 2) + (threadIdx.x >> 6);   // 0..4095
    const int r0   = lane & 15;
    const int g    = lane >> 4;

    bf16x8 bfr[40];
    const bf16x8* bp = (const bf16x8*)T1f;
#pragma unroll
    for (int q = 0; q < 40; ++q) bfr[q] = bp[q * 64 + lane];

    for (int q = 0; q < 4; ++q) {
        const int mt = (wg << 2) + q;                          // 0..16383
        const float* xp = x + (size_t)mt * (16 * 256) + r0 * 256 + 8 * g;

        f32x4 acc0 = {0,0,0,0}, acc1 = {0,0,0,0}, acc2 = {0,0,0,0},
              acc3 = {0,0,0,0}, acc4 = {0,0,0,0};
#pragma unroll
        for (int c = 0; c < 8; ++c) {
            const float* ap = xp + 32 * c;
            f32x4 lo = *(const f32x4*)ap;
            f32x4 hi = *(const f32x4*)(ap + 4);
            bf16x8 a = {(short)f2bf(lo[0]), (short)f2bf(lo[1]),
                        (short)f2bf(lo[2]), (short)f2bf(lo[3]),
                        (short)f2bf(hi[0]), (short)f2bf(hi[1]),
                        (short)f2bf(hi[2]), (short)f2bf(hi[3])};
            acc0 = __builtin_amdgcn_mfma_f32_16x16x32_bf16(a, bfr[c*5+0], acc0, 0, 0, 0);
            acc1 = __builtin_amdgcn_mfma_f32_16x16x32_bf16(a, bfr[c*5+1], acc1, 0, 0, 0);
            acc2 = __builtin_amdgcn_mfma_f32_16x16x32_bf16(a, bfr[c*5+2], acc2, 0, 0, 0);
            acc3 = __builtin_amdgcn_mfma_f32_16x16x32_bf16(a, bfr[c*5+3], acc3, 0, 0, 0);
            acc4 = __builtin_amdgcn_mfma_f32_16x16x32_bf16(a, bfr[c*5+4], acc4, 0, 0, 0);
        }

        ushort* yp = Y + (size_t)mt * (16 * 66);
#pragma unroll
        for (int j = 0; j < 4; ++j) {
            int row = 4 * g + j;
            yp[row * 66 + NB0 + r0] = f2bf(acc0[j]);
            yp[row * 66 + NB1 + r0] = f2bf(acc1[j]);
            yp[row * 66 + NB2 + r0] = f2bf(acc2[j]);
            yp[row * 66 + NB3 + r0] = f2bf(acc3[j]);
            if (r0 >= 14) yp[row * 66 + NB4 + r0] = f2bf(acc4[j]);
        }
    }
}

// ---------------------------------------------------------------------------
// K2: per plane XT[64,66] = A2[64,512] @ B2[512,66]. A2-frags in regs,
// B2 transposed in XOR-swizzled LDS. Mode-sum weights folded at store.
// ---------------------------------------------------------------------------
__global__ __launch_bounds__(256)
void fno_gemm2(const ushort* __restrict__ Y, const ushort* __restrict__ A2f,
               float* __restrict__ XTr, float* __restrict__ XTi) {
    __shared__ ushort B2t[66 * 512];          // [n=66][k=512], 16B-unit XOR swizzle
    const int tid = threadIdx.x;
    const int p   = blockIdx.x;

    // stage: B2t[2ky][2x]=Yr, [2ky][2x+1]=-Yi, [2ky+1][2x]=Yi, [2ky+1][2x+1]=Yr
    const ushort* yp = Y + (size_t)p * (256 * 66);
    uint* b32 = (uint*)B2t;
    for (int e = tid; e < 8448; e += 256) {    // e = x*33 + ky
        int xx = e / 33;
        int ky = e - 33 * xx;
        uint v = *(const uint*)(yp + xx * 66 + 2 * ky);
        uint yr = v & 0xffffu, yi = v >> 16;
        uint w0 = yr | ((yi ^ 0x8000u) << 16);
        uint w1 = yi | (yr << 16);
        int u = xx >> 2, off = xx & 3;
        int ra = 2 * ky, rb = 2 * ky + 1;
        b32[ra * 256 + ((u ^ (ra & 7)) << 2) + off] = w0;
        b32[rb * 256 + ((u ^ (rb & 7)) << 2) + off] = w1;
    }

    const int lane = tid & 63;
    const int mt   = tid >> 6;                 // wave -> M-tile (kx group)
    const int r0   = lane & 15;
    const int g    = lane >> 4;

    bf16x8 af[16];
    const bf16x8* ap = (const bf16x8*)A2f;
#pragma unroll
    for (int c = 0; c < 16; ++c) af[c] = ap[(c * 4 + mt) * 64 + lane];

    __syncthreads();

    const int nb[5] = {NB0, NB1, NB2, NB3, NB4};
    f32x4 acc[5];
#pragma unroll
    for (int t = 0; t < 5; ++t) acc[t] = (f32x4){0, 0, 0, 0};

#pragma unroll
    for (int c = 0; c < 16; ++c) {
#pragma unroll
        for (int t = 0; t < 5; ++t) {
            int row = nb[t] + r0;
            int u = (c << 2) + g;
            bf16x8 b = *(const bf16x8*)&B2t[row * 512 + ((u ^ (row & 7)) << 3)];
            acc[t] = __builtin_amdgcn_mfma_f32_16x16x32_bf16(af[c], b, acc[t], 0, 0, 0);
        }
    }

    float* dr = XTr + (size_t)p * MODES;
    float* di = XTi + (size_t)p * MODES;
#pragma unroll
    for (int t = 0; t < 5; ++t) {
        int n  = nb[t] + r0;
        int ky = n >> 1, im = n & 1;
#pragma unroll
        for (int j = 0; j < 4; ++j) {
            if (t == 4 && r0 < 14) continue;
            int kx = mt * 16 + 4 * g + j;
            float w = (kx < 32) ? ((kx == 0 && ky == 0) ? 1.f : 2.f)
                                : ((ky == 0) ? 0.f : 2.f);
            (im ? di : dr)[kx * 33 + ky] = w * acc[t][j];
        }
    }
}

// ---------------------------------------------------------------------------
// Stage 3 (unchanged from round 2): out partials over (i, m-chunk) blocks.
// ---------------------------------------------------------------------------
__global__ __launch_bounds__(256)
void fno_stage3(const float* __restrict__ XTr, const float* __restrict__ XTi,
                const float* __restrict__ Wr,  const float* __restrict__ Wi,
                float* __restrict__ part) {
    __shared__ float sm3[2][32][268];
    const int i  = blockIdx.x >> 3;
    const int mc = blockIdx.x & 7;
    const int tid = threadIdx.x;
    const size_t mbase = (size_t)mc * 264;

    for (int f = tid; f < 4224; f += 256) {
        int arr = (f >= 2112);
        int gidx = f - arr * 2112;
        int b = gidx / 66, q = gidx - b * 66;
        const float* src = (arr ? XTi : XTr) + (size_t)(b * CIn + i) * MODES + mbase + 4 * q;
        float4 v = *(const float4*)src;
        *(float4*)&sm3[arr][b][4 * q] = v;
    }
    __syncthreads();

    const int o  = tid >> 2;
    const int ms = tid & 3;
    const float* wrp = Wr + (size_t)(i * COut + o) * MODES + mbase + ms;
    const float* wip = Wi + (size_t)(i * COut + o) * MODES + mbase + ms;

    float acc[32];
#pragma unroll
    for (int b = 0; b < 32; ++b) acc[b] = 0.f;

#pragma unroll 2
    for (int t = 0; t < 66; ++t) {
        float wr = wrp[4 * t], wi = wip[4 * t];
        int m = 4 * t + ms;
#pragma unroll
        for (int b = 0; b < 32; ++b)
            acc[b] += sm3[0][b][m] * wr - sm3[1][b][m] * wi;
    }

    __syncthreads();
    float* red = &sm3[0][0][0];
#pragma unroll
    for (int b = 0; b < 32; ++b)
        red[b * 256 + o * 4 + ms] = acc[b];
    __syncthreads();

    for (int s = tid; s < 2048; s += 256) {
        int o2 = s >> 5, b2 = s & 31;
        float v = red[b2 * 256 + o2 * 4 + 0] + red[b2 * 256 + o2 * 4 + 1]
                + red[b2 * 256 + o2 * 4 + 2] + red[b2 * 256 + o2 * 4 + 3];
        part[(size_t)blockIdx.x * 2048 + s] = v;
    }
}

__global__ void fno_reduce(const float* __restrict__ part, float* __restrict__ out) {
    int idx = blockIdx.x * 256 + threadIdx.x;
    int b = idx >> 6, o = idx & 63;
    float s = 0.f;
#pragma unroll 8
    for (int j = 0; j < 256; ++j) s += part[(size_t)j * 2048 + o * 32 + b];
    out[idx] = s;
}

// ---------------------------------------------------------------------------
extern "C" void kernel_launch(void* const* d_in, const int* in_sizes, int n_in,
                              void* d_out, int out_size, void* d_ws, size_t ws_size,
                              hipStream_t stream) {
    const float* x  = (const float*)d_in[0];
    const float* wr = (const float*)d_in[1];
    const float* wi = (const float*)d_in[2];
    float* out = (float*)d_out;
    char* ws   = (char*)d_ws;

    ushort* T1f = (ushort*)(ws + OB_T1F);
    ushort* A2f = (ushort*)(ws + OB_A2F);
    ushort* Y   = (ushort*)(ws + OB_Y);
    float* XTr  = (float*)(ws + OB_XTR);
    float* XTi  = (float*)(ws + OB_XTI);
    float* part = (float*)(ws + OB_PART);

    fno_tw<<<128, 256, 0, stream>>>(T1f, A2f);
    fno_gemm1<<<1024, 256, 0, stream>>>(x, T1f, Y);
    fno_gemm2<<<1024, 256, 0, stream>>>(Y, A2f, XTr, XTi);
    fno_stage3<<<256, 256, 0, stream>>>(XTr, XTi, wr, wi, part);
    fno_reduce<<<8, 256, 0, stream>>>(part, out);
}